// Round 9
// baseline (192.005 us; speedup 1.0000x reference)
//
#include <hip/hip_runtime.h>
#include <stdint.h>
#include <stddef.h>

// CliffordLinear as one bf16 GEMM:
//   out[b, o*8+l] = sum_{i,k} X[b, i*8+k] * Wt[o*8+l, i*8+k] + bias[o*8+l]
//   Wt[(o,l),(i,k)] = sum_j cayley[j,k,l] * W[o,i,j]
// M=8192, N=2048, K=2048. bf16 MFMA 16x16x32, fp32 accumulate.
//
// R15 = R9 GEMM core + in-kernel A-cast (X stays f32; the 15-us cast
// dispatch is eliminated), done RIGHT this time:
//  - cvt ds_writes are byte-identical to R9's global_load_lds pattern:
//    linear dest lane*16 (conflict-free by construction), source f32 cols
//    pre-swizzled with R9's sgrp=(i&3)^((i>>3)&3). Verified: phys group p of
//    row r holds global group p^((r>>1)&3) == R9's layout, so R9's
//    0-conflict fragment reads (offq quad-XOR) are unchanged.
//    (R13's failure: lane->i*32 writes = 16-way conflict, 2.1M counted.)
//  - one barrier + lgkmcnt(0) per slice (64 total). Safe because every
//    wave drains its LDS reads (lgkmcnt(0)) BEFORE the barrier, so a wave
//    that passes the barrier and overwrites a slot cannot corrupt any
//    in-flight read. Slot map per slice s: read As[s&3] (af0,af1),
//    prefetch Bs[(s+1)&3]; write As[(s+2)&3] (cvt), Bs[s&3] (stage s+4).
//    All same-window and one-barrier-skew pairs disjoint (derived).
//  - vmcnt ledger (mixed queue, in-order accounting): per slice issues
//    [h0: 4x A-f32 (slice s+3)] [h1: 2x B-dma (slice s+4)]. At h1(s),
//    vmcnt(6) keeps {A(s+3),B(s+3)} and drains A(s+2) (needed for cvt) and
//    B(s+2) and older. Prologue establishes the same invariant; tail:
//    vmcnt(6) thru s=60, vmcnt(0) at s=61, none after.
//  - A-regs double set (aE/aO): issue at h0(s) -> cvt at h1(s+1).
// GEMM core otherwise R9 (best measured: 72.0 us, 0 conflicts): BM=BN=256,
// 8 waves 2Mx4N, acc[8][4], 16x16x32, setprio, XCD swizzle.
// Prep shrinks to fold-only (8 MB, ~3 us).

typedef __bf16 bf16x8 __attribute__((ext_vector_type(8)));
typedef float  f32x4  __attribute__((ext_vector_type(4)));

#define BM 256
#define BN 256
#define KSLICE 32
#define SLOT 8192            // elems per 16 KB slot

__device__ __forceinline__ void async_copy16(void* lds_dst, const void* g_src) {
    __builtin_amdgcn_global_load_lds(
        (__attribute__((address_space(1))) void*)g_src,
        (__attribute__((address_space(3))) void*)lds_dst,
        16, 0, 0);
}

__device__ __forceinline__ bf16x8 cvt2(f32x4 a, f32x4 b) {
    bf16x8 r;
    r[0] = (__bf16)a[0]; r[1] = (__bf16)a[1];
    r[2] = (__bf16)a[2]; r[3] = (__bf16)a[3];
    r[4] = (__bf16)b[0]; r[5] = (__bf16)b[1];
    r[6] = (__bf16)b[2]; r[7] = (__bf16)b[3];
    return r;
}

// ---------------- kernel 1: fold Cayley into W (row-major Wt [N][K]) ------
// R9's verified fold branch, standalone.
__global__ __launch_bounds__(256) void fold_kernel(
    const float* __restrict__ W, const float* __restrict__ cayley,
    __bf16* __restrict__ Wt, int Cin, int Cout)
{
    __shared__ float Cay[512];
    for (int t = threadIdx.x; t < 512; t += 256) Cay[t] = cayley[t];
    __syncthreads();

    int flat = blockIdx.x * 256 + threadIdx.x;   // n*Cin + i
    int total = Cout * 8 * Cin;
    if (flat >= total) return;
    int i = flat % Cin;
    int n = flat / Cin;
    int o = n >> 3, l = n & 7;

    const float* wrow = W + ((size_t)o * Cin + i) * 8;
    float w8[8];
    #pragma unroll
    for (int j = 0; j < 8; ++j) w8[j] = wrow[j];

    bf16x8 outv;
    #pragma unroll
    for (int k = 0; k < 8; ++k) {
        float s = 0.f;
        #pragma unroll
        for (int j = 0; j < 8; ++j) s += Cay[j * 64 + k * 8 + l] * w8[j];
        outv[k] = (__bf16)s;
    }
    *(bf16x8*)(Wt + (size_t)n * (Cin * 8) + i * 8) = outv;
}

// ---------------- kernel 2: bf16 GEMM with fused A-cast -------------------
// X  : [M][K] f32 ; Wt : [N][K] bf16 ; C : [M][N] f32
__global__ __launch_bounds__(512, 2) void gemm_bt_kernel(
    const float*  __restrict__ X,
    const __bf16* __restrict__ Bt,
    const float*  __restrict__ bias,
    float* __restrict__ C,
    int M, int N, int K)
{
    __shared__ __align__(16) __bf16 As[4][SLOT];  // 4 x 16 KB
    __shared__ __align__(16) __bf16 Bs[4][SLOT];  // 4 x 16 KB

    const int tid  = threadIdx.x;
    const int wave = tid >> 6;    // 0..7
    const int lane = tid & 63;
    const int quad = lane >> 4;
    const int l16  = lane & 15;

    // --- XCD swizzle: 256 blocks, 8 XCDs; bijective since 256%8==0.
    const int bid = blockIdx.x;
    const int xcd = bid & 7;
    const int idx = bid >> 3;
    const int mBase = (xcd * 4 + (idx & 3)) * BM;
    const int nBase = (idx >> 2) * BN;

    // --- staging addressing (R9 source swizzle) ---
    const int srow = lane >> 2;                       // 0..15
    const int sgrp = (lane & 3) ^ ((lane >> 3) & 3);  // swizzled 16B group
    // A (f32 source, cast in-kernel): chunk0 rows wave*32+srow, chunk1 +16.
    const float* gXc0 = X + (size_t)(mBase + wave * 32 +  0 + srow) * K + sgrp * 8;
    const float* gXc1 = X + (size_t)(mBase + wave * 32 + 16 + srow) * K + sgrp * 8;
    // B (bf16 DMA, R9 verbatim)
    const __bf16* gB0 = Bt + (size_t)(nBase + wave * 32 +  0 + srow) * K + sgrp * 8;
    const __bf16* gB1 = Bt + (size_t)(nBase + wave * 32 + 16 + srow) * K + sgrp * 8;
    const int stOff = wave * 1024;                 // elems
    // cvt write dest: LINEAR lane*16B within chunk == gload_lds scatter.
    const int wdA0 = stOff + lane * 8;             // chunk0 elem offset
    const int wdA1 = stOff + 512 + lane * 8;       // chunk1

#define ISSUE_A(SET, q) do {                                       \
        SET[0] = *(const f32x4*)(gXc0 + (size_t)(q) * KSLICE);     \
        SET[1] = *(const f32x4*)(gXc0 + (size_t)(q) * KSLICE + 4); \
        SET[2] = *(const f32x4*)(gXc1 + (size_t)(q) * KSLICE);     \
        SET[3] = *(const f32x4*)(gXc1 + (size_t)(q) * KSLICE + 4); \
    } while (0)
#define CVT_WRITE(SET, slot) do {                                  \
        *(bf16x8*)&As[slot][wdA0] = cvt2(SET[0], SET[1]);          \
        *(bf16x8*)&As[slot][wdA1] = cvt2(SET[2], SET[3]);          \
    } while (0)
#define STAGE_B(slot, q) do {                                              \
        async_copy16(&Bs[slot][stOff      ], gB0 + (size_t)(q) * KSLICE);  \
        async_copy16(&Bs[slot][stOff + 512], gB1 + (size_t)(q) * KSLICE);  \
    } while (0)

    // --- compute: wave (wm,wn) owns 128x64; R9 fragment pattern (0-confl).
    const int wm = wave >> 2;
    const int wn = wave & 3;
    const int offq = (quad ^ ((l16 >> 1) & 3)) * 8;
    const __bf16* paBase = &As[0][(wm * 128 + l16) * KSLICE + offq];
    const __bf16* pbBase = &Bs[0][(wn * 64  + l16) * KSLICE + offq];

    f32x4 acc[8][4] = {};
    bf16x8 af0[4], af1[4], bfA[4], bfB[4];
    f32x4 aE[4], aO[4];

    // --- prologue (ledger in comments):
    // issue A0->aE, A1->aO, B0, B1                       [12 out]
    ISSUE_A(aE, 0); ISSUE_A(aO, 1);
    STAGE_B(0, 0);  STAGE_B(1, 1);
    asm volatile("s_waitcnt vmcnt(8)" ::: "memory");   // A0 done
    CVT_WRITE(aE, 0);
    asm volatile("s_waitcnt vmcnt(4)" ::: "memory");   // A1 done (B0,B1 fly)
    CVT_WRITE(aO, 1);
    ISSUE_A(aO, 2);                                    // slice-2 A -> aO
    STAGE_B(2, 2); STAGE_B(3, 3);                      // [B0,B1,A2,B2,B3]=12
    asm volatile("s_waitcnt vmcnt(8)" ::: "memory");   // B0,B1 done
    asm volatile("s_waitcnt lgkmcnt(0)" ::: "memory"); // publish cvt writes
    __builtin_amdgcn_s_barrier();
    // preload slice-0 B frags
    #pragma unroll
    for (int n = 0; n < 4; ++n)
        bfA[n] = *(const bf16x8*)(pbBase + n * 512);

    // One slice (single barrier):
    //  read af0,af1 <- As[s&3] | ISSUE_A(s+3) | MFMA m0-3 (af0,BF)
    //  | vmcnt | STAGE_B(Bs[s&3], s+4) | CVT(aCvt -> As[(s+2)&3])
    //  | prefetch NBF <- Bs[(s+1)&3] | MFMA m4-7 (af1,BF)
    //  | lgkmcnt(0) | barrier
    // VM: 0 -> vmcnt(6); 1 -> vmcnt(0); 2 -> none.
#define SLICE(s_, SC, SN, BF, NBF, AIS, ACV, DOA, DOB, DOCVT, DOPF, VM)        \
    do {                                                                       \
        _Pragma("unroll")                                                      \
        for (int m = 0; m < 4; ++m)                                            \
            af0[m] = *(const bf16x8*)(paBase + (SC) * SLOT + m * 512);         \
        if (DOA) ISSUE_A(AIS, (s_) + 3);                                       \
        __builtin_amdgcn_s_setprio(1);                                         \
        _Pragma("unroll")                                                      \
        for (int m = 0; m < 4; ++m)                                            \
            _Pragma("unroll")                                                  \
            for (int n = 0; n < 4; ++n)                                        \
                acc[m][n] = __builtin_amdgcn_mfma_f32_16x16x32_bf16(           \
                    af0[m], BF[n], acc[m][n], 0, 0, 0);                        \
        __builtin_amdgcn_s_setprio(0);                                         \
        if ((VM) == 0)      asm volatile("s_waitcnt vmcnt(6)" ::: "memory");   \
        else if ((VM) == 1) asm volatile("s_waitcnt vmcnt(0)" ::: "memory");   \
        if (DOB) STAGE_B((s_) & 3, (s_) + 4);                                  \
        if (DOCVT) CVT_WRITE(ACV, ((s_) + 2) & 3);                             \
        _Pragma("unroll")                                                      \
        for (int m = 0; m < 4; ++m)                                            \
            af1[m] = *(const bf16x8*)(paBase + (SC) * SLOT + 2048 + m * 512);  \
        if (DOPF) {                                                            \
            _Pragma("unroll")                                                  \
            for (int n = 0; n < 4; ++n)                                        \
                NBF[n] = *(const bf16x8*)(pbBase + (SN) * SLOT + n * 512);     \
        }                                                                      \
        __builtin_amdgcn_s_setprio(1);                                         \
        _Pragma("unroll")                                                      \
        for (int m = 0; m < 4; ++m)                                            \
            _Pragma("unroll")                                                  \
            for (int n = 0; n < 4; ++n)                                        \
                acc[4 + m][n] = __builtin_amdgcn_mfma_f32_16x16x32_bf16(       \
                    af1[m], BF[n], acc[4 + m][n], 0, 0, 0);                    \
        __builtin_amdgcn_s_setprio(0);                                         \
        asm volatile("s_waitcnt lgkmcnt(0)" ::: "memory");                     \
        __builtin_amdgcn_s_barrier();                                          \
    } while (0)

    // --- main loop: slices 0..55 (14 x 4; slot period 4, parity period 2).
    // Parity: even s -> issue aE / cvt aO / BF=bfA; odd s -> the mirror.
    #pragma unroll 1
    for (int t = 0; t < 14; ++t) {
        SLICE(4 * t + 0, 0, 1, bfA, bfB, aE, aO, true, true, true, true, 0);
        SLICE(4 * t + 1, 1, 2, bfB, bfA, aO, aE, true, true, true, true, 0);
        SLICE(4 * t + 2, 2, 3, bfA, bfB, aE, aO, true, true, true, true, 0);
        SLICE(4 * t + 3, 3, 0, bfB, bfA, aO, aE, true, true, true, true, 0);
    }
    // --- tail slices 56..63.
    SLICE(56, 0, 1, bfA, bfB, aE, aO, true,  true,  true,  true,  0);
    SLICE(57, 1, 2, bfB, bfA, aO, aE, true,  true,  true,  true,  0);
    SLICE(58, 2, 3, bfA, bfB, aE, aO, true,  true,  true,  true,  0);
    SLICE(59, 3, 0, bfB, bfA, aO, aE, true,  true,  true,  true,  0);
    SLICE(60, 0, 1, bfA, bfB, aE, aO, true,  false, true,  true,  0);  // A63; no B-stage
    SLICE(61, 1, 2, bfB, bfA, aO, aE, false, false, true,  true,  1);  // vmcnt0; cvt A63
    SLICE(62, 2, 3, bfA, bfB, aE, aO, false, false, false, true,  2);
    SLICE(63, 3, 0, bfB, bfA, aO, aE, false, false, false, false, 2);

#undef SLICE
#undef STAGE_B
#undef CVT_WRITE
#undef ISSUE_A

    // --- epilogue: C/D layout col = lane&15, row = quad*4 + reg (R9).
    float bv[4];
    #pragma unroll
    for (int n = 0; n < 4; ++n)
        bv[n] = bias[nBase + wn * 64 + n * 16 + l16];

    #pragma unroll
    for (int m = 0; m < 8; ++m) {
        #pragma unroll
        for (int n = 0; n < 4; ++n) {
            const int col = nBase + wn * 64 + n * 16 + l16;
            #pragma unroll
            for (int r = 0; r < 4; ++r) {
                const int row = mBase + wm * 128 + m * 16 + quad * 4 + r;
                C[(size_t)row * N + col] = acc[m][n][r] + bv[n];
            }
        }
    }
}

extern "C" void kernel_launch(void* const* d_in, const int* in_sizes, int n_in,
                              void* d_out, int out_size, void* d_ws, size_t ws_size,
                              hipStream_t stream) {
    const float* x      = (const float*)d_in[0];  // [B][Cin][8]
    const float* weight = (const float*)d_in[1];  // [Cout][Cin][8]
    const float* bias   = (const float*)d_in[2];  // [Cout][8]
    const float* cayley = (const float*)d_in[3];  // [8][8][8]
    float* out = (float*)d_out;                   // [B][Cout][8]

    const int Cout = in_sizes[2] / 8;
    const int Cin  = in_sizes[1] / (Cout * 8);
    const int Bm   = in_sizes[0] / (Cin * 8);
    const int M = Bm;          // 8192
    const int N = Cout * 8;    // 2048
    const int K = Cin * 8;     // 2048

    __bf16* Wt = (__bf16*)d_ws;   // N*K bf16 = 8 MB, row-major

    // 1) fold only (X-cast dispatch eliminated; GEMM casts A in-kernel)
    int foldBlocks = (N * Cin + 255) / 256;   // 2048
    fold_kernel<<<foldBlocks, 256, 0, stream>>>(weight, cayley, Wt, Cin, Cout);

    // 2) GEMM: 256x256 tiles, 32 x 8 = 256 blocks, 512 threads (8 waves)
    int grid = (M / BM) * (N / BN);
    gemm_bt_kernel<<<grid, 512, 0, stream>>>(x, Wt, bias, out, M, N, K);
}